// Round 1
// baseline (3343.382 us; speedup 1.0000x reference)
//
#include <hip/hip_runtime.h>

#define N_PIX 4096
#define HW 64

__device__ __forceinline__ unsigned fmap_desc(float f) {
    unsigned u = __float_as_uint(f);
    unsigned m = u ^ (((unsigned)((int)u >> 31)) | 0x80000000u); // ascending map
    return ~m;                                                   // descending
}

extern "C" __global__ void __launch_bounds__(256)
ph0_diagram_kernel(const float* __restrict__ logits,
                   const float* __restrict__ target,
                   float* __restrict__ wsB, int* __restrict__ wsK) {
    __shared__ float s_vals[N_PIX];                 // 16 KB
    __shared__ unsigned long long s_key[N_PIX];     // 32 KB
    __shared__ unsigned short s_order[N_PIX];       // 8 KB
    __shared__ unsigned short s_rank[N_PIX];        // 8 KB
    __shared__ unsigned short s_parent[N_PIX];      // 8 KB
    __shared__ unsigned int s_bars[N_PIX];          // 16 KB
    __shared__ int s_cnt;

    const int d = blockIdx.x;        // 0..3 pred, 4..7 target
    const int s = d & 3;
    const bool is_pred = d < 4;
    const int tid = threadIdx.x;

    // ---- load values (pred = softmax(logits,ch)[1], exact jax formula) ----
    for (int p = tid; p < N_PIX; p += 256) {
        float v;
        if (is_pred) {
            float l0 = logits[s * 2 * N_PIX + p];
            float l1 = logits[s * 2 * N_PIX + N_PIX + p];
            float m = fmaxf(l0, l1);
            float e0 = expf(l0 - m), e1 = expf(l1 - m);
            v = e1 / (e0 + e1);
        } else {
            v = target[s * N_PIX + p];
        }
        s_vals[p] = v;
        s_key[p] = ((unsigned long long)fmap_desc(v) << 32) | (unsigned)p;
        s_bars[p] = 0xFFFFFFFFu;
    }
    __syncthreads();

    // ---- bitonic sort pixel keys ascending == (value desc, idx asc) ----
    for (unsigned k = 2; k <= N_PIX; k <<= 1) {
        for (unsigned j = k >> 1; j > 0; j >>= 1) {
            for (unsigned idx = tid; idx < N_PIX; idx += 256) {
                unsigned ixj = idx ^ j;
                if (ixj > idx) {
                    unsigned long long a = s_key[idx], b = s_key[ixj];
                    bool up = ((idx & k) == 0);
                    if ((a > b) == up) { s_key[idx] = b; s_key[ixj] = a; }
                }
            }
            __syncthreads();
        }
    }

    // ---- order / rank / parent init ----
    for (int t = tid; t < N_PIX; t += 256) {
        int p = (int)(s_key[t] & 0xFFFFFFFFu);
        s_order[t] = (unsigned short)p;
        s_rank[p] = (unsigned short)t;
        s_parent[p] = (unsigned short)p;
    }
    __syncthreads();

    // ---- sequential elder-rule union-find (faithful to reference) ----
    if (tid == 0) {
        int cnt = 0;
        const float minv = s_vals[s_order[N_PIX - 1]];
        const float maxv = s_vals[s_order[0]];
        for (int t = 0; t < N_PIX; ++t) {
            const int i = s_order[t];
            int ri = i;
            float vri = s_vals[i];
            const float vd = vri;  // death value = current pixel value
            const int r = i >> 6, c = i & 63;
            #pragma unroll
            for (int k = 0; k < 4; ++k) {   // order: up, down, left, right
                int j;
                if (k == 0) { if (r == 0)  continue; j = i - HW; }
                else if (k == 1) { if (r == 63) continue; j = i + HW; }
                else if (k == 2) { if (c == 0)  continue; j = i - 1; }
                else            { if (c == 63) continue; j = i + 1; }
                if ((int)s_rank[j] > t) continue;     // j not added yet
                // find(j) with path halving (roots unchanged vs reference)
                int rj = j;
                while (true) {
                    int p = s_parent[rj];
                    if (p == rj) break;
                    int gp = s_parent[p];
                    s_parent[rj] = (unsigned short)gp;
                    rj = gp;
                }
                if (rj == ri) continue;
                const float vrj = s_vals[rj];
                int young; float vy;
                if (vri >= vrj) {            // tie -> ri elder (matches ref)
                    young = rj; vy = vrj;
                    s_parent[rj] = (unsigned short)ri;
                } else {
                    young = ri; vy = vri;
                    s_parent[ri] = (unsigned short)rj;
                    ri = rj; vri = vrj;
                }
                if (vy > vd)                 // only positive-persistence bars matter
                    s_bars[cnt++] = ((unsigned)young << 16) | (unsigned)i;
            }
        }
        // essential bar: final root has global max value, dies at global min
        if (maxv > minv)
            s_bars[cnt++] = ((unsigned)s_order[0] << 16) | (unsigned)s_order[N_PIX - 1];
        s_cnt = cnt;
    }
    __syncthreads();

    // ---- bitonic sort bars by persistence DESC (sentinel p = -1 sinks) ----
    for (unsigned k = 2; k <= N_PIX; k <<= 1) {
        for (unsigned j = k >> 1; j > 0; j >>= 1) {
            for (unsigned idx = tid; idx < N_PIX; idx += 256) {
                unsigned ixj = idx ^ j;
                if (ixj > idx) {
                    unsigned a = s_bars[idx], b = s_bars[ixj];
                    float pa = (a == 0xFFFFFFFFu) ? -1.0f
                             : s_vals[a >> 16] - s_vals[a & 0xFFFFu];
                    float pb = (b == 0xFFFFFFFFu) ? -1.0f
                             : s_vals[b >> 16] - s_vals[b & 0xFFFFu];
                    bool up = ((idx & k) == 0);
                    if ((pa < pb) == up) { s_bars[idx] = b; s_bars[ixj] = a; }
                }
            }
            __syncthreads();
        }
    }

    // ---- write sorted (birth, death) values + count ----
    float* B = wsB + d * 2 * N_PIX;
    float* D = B + N_PIX;
    for (int t = tid; t < N_PIX; t += 256) {
        unsigned bar = s_bars[t];
        float b = 0.0f, dd = 0.0f;
        if (bar != 0xFFFFFFFFu) {
            b = s_vals[bar >> 16];
            dd = s_vals[bar & 0xFFFFu];
        }
        B[t] = b; D[t] = dd;
    }
    if (tid == 0) wsK[d] = s_cnt;
}

extern "C" __global__ void __launch_bounds__(256)
betti_loss_kernel(const float* __restrict__ wsB, const int* __restrict__ wsK,
                  float* __restrict__ out) {
    const int s = blockIdx.x;                 // sample
    const float* B1 = wsB + s * 2 * N_PIX;
    const float* D1 = B1 + N_PIX;
    const float* B2 = wsB + (4 + s) * 2 * N_PIX;
    const float* D2 = B2 + N_PIX;
    const int K1 = wsK[s], K2 = wsK[4 + s];
    const int mn = min(K1, K2);
    const int tid = threadIdx.x;

    float acc = 0.0f;
    for (int t = tid; t < N_PIX; t += 256) {
        if (t < mn) {
            float db = B1[t] - B2[t];
            float dd = D1[t] - D2[t];
            acc += db * db + dd * dd;
        } else {
            if (t < K1) { float e = B1[t] - D1[t]; acc += 0.5f * e * e; }
            if (t < K2) { float e = B2[t] - D2[t]; acc += 0.5f * e * e; }
        }
    }
    // block reduction (4 waves of 64)
    for (int off = 32; off > 0; off >>= 1) acc += __shfl_down(acc, off);
    __shared__ float red[4];
    const int wid = tid >> 6, lane = tid & 63;
    if (lane == 0) red[wid] = acc;
    __syncthreads();
    if (tid == 0) {
        float tsum = red[0] + red[1] + red[2] + red[3];
        atomicAdd(out, 0.25f * tsum);
    }
}

extern "C" void kernel_launch(void* const* d_in, const int* in_sizes, int n_in,
                              void* d_out, int out_size, void* d_ws, size_t ws_size,
                              hipStream_t stream) {
    const float* logits = (const float*)d_in[0];   // (4,2,64,64) f32
    const float* target = (const float*)d_in[1];   // (4,64,64) f32
    float* wsB = (float*)d_ws;                     // 8 diagrams * 2 * 4096 floats
    int* wsK = (int*)((char*)d_ws + (size_t)8 * 2 * N_PIX * sizeof(float));

    hipMemsetAsync(d_out, 0, sizeof(float), stream);
    hipLaunchKernelGGL(ph0_diagram_kernel, dim3(8), dim3(256), 0, stream,
                       logits, target, wsB, wsK);
    hipLaunchKernelGGL(betti_loss_kernel, dim3(4), dim3(256), 0, stream,
                       wsB, wsK, (float*)d_out);
}

// Round 2
// 1584.265 us; speedup vs baseline: 2.1104x; 2.1104x over previous
//
#include <hip/hip_runtime.h>

#define N_PIX 4096
#define HW 64
#define NBARS 2048

__device__ __forceinline__ unsigned fmap_desc(float f) {
    unsigned u = __float_as_uint(f);
    unsigned m = u ^ (((unsigned)((int)u >> 31)) | 0x80000000u); // ascending map
    return ~m;                                                   // descending
}
__device__ __forceinline__ float funmap_desc(unsigned k) {
    unsigned m = ~k;
    unsigned u = (m & 0x80000000u) ? (m ^ 0x80000000u) : ~m;
    return __uint_as_float(u);
}

// labels for added (earlier-rank) neighbors of the pixel at rank t
__device__ __forceinline__ int gather_labs(int t,
                                           const unsigned short* s_order,
                                           const unsigned short* s_rank,
                                           const unsigned short* s_plab,
                                           unsigned short labs[4]) {
    int i = s_order[t];
    int r = i >> 6, c = i & 63;
    int nl = 0;
    if (r > 0  && (int)s_rank[i - HW] < t) labs[nl++] = s_plab[i - HW];
    if (r < 63 && (int)s_rank[i + HW] < t) labs[nl++] = s_plab[i + HW];
    if (c > 0  && (int)s_rank[i - 1]  < t) labs[nl++] = s_plab[i - 1];
    if (c < 63 && (int)s_rank[i + 1]  < t) labs[nl++] = s_plab[i + 1];
    return nl;
}

extern "C" __global__ void __launch_bounds__(256)
ph0_diagram_kernel(const float* __restrict__ logits,
                   const float* __restrict__ target,
                   float* __restrict__ wsB, int* __restrict__ wsK) {
    __shared__ unsigned long long s_key[N_PIX];   // 32KB: sort keys -> events -> bar keys
    __shared__ unsigned short s_rank[N_PIX];      // 8KB: rank -> parent (aliased later)
    __shared__ unsigned short s_order[N_PIX];     // 8KB: order -> bars u32[2048] (aliased)
    __shared__ unsigned short s_plab[N_PIX];      // 8KB: peak label (pixel id -> peak rank)
    __shared__ float s_vrk[N_PIX];                // 16KB: value by rank (descending)
    __shared__ unsigned short s_evrank[N_PIX];    // 8KB: event pixel rank
    __shared__ int s_tsum[257];
    __shared__ int s_nev, s_cnt;

    ushort4*        s_evt    = (ushort4*)s_key;        // events: 4 peak-rank labels
    unsigned int*   s_bars   = (unsigned int*)s_order; // (birth_rank<<16)|death_rank
    unsigned short* s_parent = s_rank;                 // union-find over peak ranks

    const int d = blockIdx.x;        // 0..3 pred, 4..7 target
    const int smp = d & 3;
    const bool is_pred = d < 4;
    const int tid = threadIdx.x;

    // ---- P0: values -> 64-bit sort keys (value desc, idx asc) ----
    for (int p = tid; p < N_PIX; p += 256) {
        float v;
        if (is_pred) {
            float l0 = logits[smp * 2 * N_PIX + p];
            float l1 = logits[smp * 2 * N_PIX + N_PIX + p];
            float m = fmaxf(l0, l1);
            float e0 = expf(l0 - m), e1 = expf(l1 - m);
            v = e1 / (e0 + e1);
        } else {
            v = target[smp * N_PIX + p];
        }
        s_key[p] = ((unsigned long long)fmap_desc(v) << 32) | (unsigned)p;
    }
    __syncthreads();

    // ---- P1: bitonic sort 4096 keys ascending ----
    for (unsigned k = 2; k <= N_PIX; k <<= 1) {
        for (unsigned j = k >> 1; j > 0; j >>= 1) {
            for (unsigned idx = tid; idx < N_PIX; idx += 256) {
                unsigned ixj = idx ^ j;
                if (ixj > idx) {
                    unsigned long long a = s_key[idx], b = s_key[ixj];
                    bool up = ((idx & k) == 0);
                    if ((a > b) == up) { s_key[idx] = b; s_key[ixj] = a; }
                }
            }
            __syncthreads();
        }
    }
    for (int t = tid; t < N_PIX; t += 256) {
        unsigned long long kk = s_key[t];
        int p = (int)(kk & 0xFFFFFFFFull);
        s_order[t] = (unsigned short)p;
        s_rank[p] = (unsigned short)t;
        s_vrk[t] = funmap_desc((unsigned)(kk >> 32));
    }
    __syncthreads();

    // ---- P2: steepest-ascent forest + pointer jumping -> peak label ----
    for (int p = tid; p < N_PIX; p += 256) {
        int r = p >> 6, c = p & 63;
        int best = s_rank[p], bj = p;
        if (r > 0)  { int t2 = s_rank[p - HW]; if (t2 < best) { best = t2; bj = p - HW; } }
        if (r < 63) { int t2 = s_rank[p + HW]; if (t2 < best) { best = t2; bj = p + HW; } }
        if (c > 0)  { int t2 = s_rank[p - 1];  if (t2 < best) { best = t2; bj = p - 1; } }
        if (c < 63) { int t2 = s_rank[p + 1];  if (t2 < best) { best = t2; bj = p + 1; } }
        s_plab[p] = (unsigned short)bj;
    }
    __syncthreads();
    for (int it = 0; it < 12; ++it) {  // paths up to 4095 -> 12 doubling rounds
        for (int p = tid; p < N_PIX; p += 256) {
            unsigned short a = s_plab[p];
            s_plab[p] = s_plab[a];
        }
        __syncthreads();
    }
    // convert peak pixel-id labels to peak RANK labels (own-entry only: race-free)
    for (int p = tid; p < N_PIX; p += 256) s_plab[p] = s_rank[s_plab[p]];
    __syncthreads();

    // ---- P3 pass1: count candidate merge events per 16-rank chunk ----
    const int base = tid * 16;
    int mycnt = 0;
    for (int t = base; t < base + 16; ++t) {
        unsigned short labs[4];
        int nl = gather_labs(t, s_order, s_rank, s_plab, labs);
        bool ev = false;
        for (int q = 1; q < nl; ++q) ev |= (labs[q] != labs[0]);
        mycnt += ev ? 1 : 0;
    }
    s_tsum[tid] = mycnt;
    __syncthreads();
    for (int off = 1; off < 256; off <<= 1) {   // Hillis-Steele inclusive scan
        int v = s_tsum[tid];
        int u = (tid >= off) ? s_tsum[tid - off] : 0;
        __syncthreads();
        s_tsum[tid] = v + u;
        __syncthreads();
    }
    if (tid == 255) s_nev = s_tsum[255];

    // ---- P3 pass2: scatter compacted events (rank order preserved) ----
    int eoff = s_tsum[tid] - mycnt;
    for (int t = base; t < base + 16; ++t) {
        unsigned short labs[4];
        int nl = gather_labs(t, s_order, s_rank, s_plab, labs);
        bool ev = false;
        for (int q = 1; q < nl; ++q) ev |= (labs[q] != labs[0]);
        if (ev) {
            for (int q = nl; q < 4; ++q) labs[q] = 0xFFFF;
            ushort4 rec; rec.x = labs[0]; rec.y = labs[1]; rec.z = labs[2]; rec.w = labs[3];
            s_evt[eoff] = rec;
            s_evrank[eoff] = (unsigned short)t;
            ++eoff;
        }
    }
    __syncthreads();

    // ---- parent init (aliases s_rank; rank no longer needed) ----
    for (int t = tid; t < N_PIX; t += 256) s_parent[t] = (unsigned short)t;
    __syncthreads();

    // ---- P4: serial elder-rule union-find over compacted events ----
    if (tid == 0) {
        int cnt = 0;
        const int nev = s_nev;
        ushort4 Lc; int tc = 0;
        if (nev > 0) { Lc = s_evt[0]; tc = s_evrank[0]; }
        for (int e = 0; e < nev; ++e) {
            ushort4 L = Lc; int t = tc;
            if (e + 1 < nev) { Lc = s_evt[e + 1]; tc = s_evrank[e + 1]; } // prefetch
            unsigned short ls[4] = { L.x, L.y, L.z, L.w };
            // batched independent 1st & 2nd hops (pipelined LDS latency)
            int p1[4], p2[4];
            p1[0] = s_parent[ls[0] & 4095]; p1[1] = s_parent[ls[1] & 4095];
            p1[2] = s_parent[ls[2] & 4095]; p1[3] = s_parent[ls[3] & 4095];
            p2[0] = s_parent[p1[0]]; p2[1] = s_parent[p1[1]];
            p2[2] = s_parent[p1[2]]; p2[3] = s_parent[p1[3]];
            int rts[4]; int nr = 0;
            #pragma unroll
            for (int q = 0; q < 4; ++q) {
                if (ls[q] == 0xFFFF) continue;
                int x;
                if (p2[q] == p1[q]) x = p1[q];
                else {
                    x = p2[q];
                    while (true) {
                        int a = s_parent[x];
                        if (a == x) break;
                        int b = s_parent[a];
                        s_parent[x] = (unsigned short)b;
                        x = b;
                    }
                }
                s_parent[ls[q]] = (unsigned short)x;  // full compression (store only)
                bool dup = false;
                for (int w = 0; w < nr; ++w) dup |= (rts[w] == x);
                if (!dup) rts[nr++] = x;
            }
            if (nr >= 2) {
                int elder = rts[0];
                for (int w = 1; w < nr; ++w) if (rts[w] < elder) elder = rts[w];
                float vd = s_vrk[t];
                for (int w = 0; w < nr; ++w) {
                    int rr = rts[w];
                    if (rr == elder) continue;
                    s_parent[rr] = (unsigned short)elder;
                    if (s_vrk[rr] > vd)   // strictly positive persistence only
                        s_bars[cnt++] = ((unsigned)rr << 16) | (unsigned)t;
                }
            }
        }
        // essential bar: global max born, dies at global min
        if (s_vrk[0] > s_vrk[N_PIX - 1])
            s_bars[cnt++] = (0u << 16) | (unsigned)(N_PIX - 1);
        s_cnt = cnt;
    }
    __syncthreads();

    // ---- P5: sort bars by persistence desc (2048-wide bitonic) ----
    const int bc = s_cnt;
    unsigned long long* s_bk = s_key;  // events dead, reuse
    for (int t = tid; t < NBARS; t += 256) {
        unsigned long long k;
        if (t < bc) {
            unsigned bb = s_bars[t];
            float pers = s_vrk[bb >> 16] - s_vrk[bb & 0xFFFFu];  // >= 0
            k = ((unsigned long long)(~__float_as_uint(pers)) << 32) | bb;
        } else k = ~0ull;
        s_bk[t] = k;
    }
    __syncthreads();
    for (unsigned k = 2; k <= NBARS; k <<= 1) {
        for (unsigned j = k >> 1; j > 0; j >>= 1) {
            for (unsigned idx = tid; idx < NBARS; idx += 256) {
                unsigned ixj = idx ^ j;
                if (ixj > idx) {
                    unsigned long long a = s_bk[idx], b = s_bk[ixj];
                    bool up = ((idx & k) == 0);
                    if ((a > b) == up) { s_bk[idx] = b; s_bk[ixj] = a; }
                }
            }
            __syncthreads();
        }
    }

    // ---- P6: write (birth, death) values + count ----
    float* B = wsB + d * 2 * NBARS;
    float* D = B + NBARS;
    for (int t = tid; t < NBARS; t += 256) {
        float b = 0.0f, dd = 0.0f;
        if (t < bc) {
            unsigned bb = (unsigned)(s_bk[t] & 0xFFFFFFFFull);
            b = s_vrk[bb >> 16];
            dd = s_vrk[bb & 0xFFFFu];
        }
        B[t] = b; D[t] = dd;
    }
    if (tid == 0) wsK[d] = bc;
}

extern "C" __global__ void __launch_bounds__(256)
betti_loss_kernel(const float* __restrict__ wsB, const int* __restrict__ wsK,
                  float* __restrict__ out) {
    const int s = blockIdx.x;
    const float* B1 = wsB + s * 2 * NBARS;
    const float* D1 = B1 + NBARS;
    const float* B2 = wsB + (4 + s) * 2 * NBARS;
    const float* D2 = B2 + NBARS;
    const int K1 = wsK[s], K2 = wsK[4 + s];
    const int mn = min(K1, K2);
    const int tid = threadIdx.x;

    float acc = 0.0f;
    for (int t = tid; t < NBARS; t += 256) {
        if (t < mn) {
            float db = B1[t] - B2[t];
            float dd = D1[t] - D2[t];
            acc += db * db + dd * dd;
        } else {
            if (t < K1) { float e = B1[t] - D1[t]; acc += 0.5f * e * e; }
            if (t < K2) { float e = B2[t] - D2[t]; acc += 0.5f * e * e; }
        }
    }
    for (int off = 32; off > 0; off >>= 1) acc += __shfl_down(acc, off);
    __shared__ float red[4];
    const int wid = tid >> 6, lane = tid & 63;
    if (lane == 0) red[wid] = acc;
    __syncthreads();
    if (tid == 0) {
        float tsum = red[0] + red[1] + red[2] + red[3];
        atomicAdd(out, 0.25f * tsum);
    }
}

extern "C" void kernel_launch(void* const* d_in, const int* in_sizes, int n_in,
                              void* d_out, int out_size, void* d_ws, size_t ws_size,
                              hipStream_t stream) {
    const float* logits = (const float*)d_in[0];   // (4,2,64,64) f32
    const float* target = (const float*)d_in[1];   // (4,64,64) f32
    float* wsB = (float*)d_ws;                     // 8 diagrams * 2 * 2048 floats
    int* wsK = (int*)((char*)d_ws + (size_t)8 * 2 * NBARS * sizeof(float));

    hipMemsetAsync(d_out, 0, sizeof(float), stream);
    hipLaunchKernelGGL(ph0_diagram_kernel, dim3(8), dim3(256), 0, stream,
                       logits, target, wsB, wsK);
    hipLaunchKernelGGL(betti_loss_kernel, dim3(4), dim3(256), 0, stream,
                       wsB, wsK, (float*)d_out);
}

// Round 3
// 1139.876 us; speedup vs baseline: 2.9331x; 1.3899x over previous
//
#include <hip/hip_runtime.h>

#define N_PIX 4096
#define HW 64
#define NBARS 2048
#define NCHUNK 16
#define CHUNK 256

__device__ __forceinline__ unsigned fmap_desc(float f) {
    unsigned u = __float_as_uint(f);
    unsigned m = u ^ (((unsigned)((int)u >> 31)) | 0x80000000u); // ascending map
    return ~m;                                                   // descending
}
__device__ __forceinline__ float funmap_desc(unsigned k) {
    unsigned m = ~k;
    unsigned u = (m & 0x80000000u) ? (m ^ 0x80000000u) : ~m;
    return __uint_as_float(u);
}

extern "C" __global__ void __launch_bounds__(256)
ph0_diagram_kernel(const float* __restrict__ logits,
                   const float* __restrict__ target,
                   float* __restrict__ wsB, int* __restrict__ wsK) {
    __shared__ unsigned long long s_key[N_PIX];   // 32KB: sort keys -> bar sort keys
    __shared__ unsigned short s_rank[N_PIX];      // 8KB: pixel -> rank
    __shared__ unsigned short s_order[N_PIX];     // 8KB: rank -> pixel
    __shared__ unsigned short s_plab[N_PIX];      // 8KB: pixel -> peak-rank label
    __shared__ unsigned short s_parent[N_PIX];    // 8KB: union-find over peak ranks
    __shared__ float s_vrk[N_PIX];                // 16KB: value by rank (descending)
    __shared__ unsigned int s_bars[NBARS];        // 8KB: (birth_rank<<16)|death_rank
    __shared__ ushort4 s_hint[CHUNK];             // 2KB: snapshot roots per event
    __shared__ unsigned short s_evr[CHUNK];       // 0.5KB: event rank
    __shared__ int s_wc[4];
    __shared__ int s_cnt;

    const int d = blockIdx.x;        // 0..3 pred, 4..7 target
    const int smp = d & 3;
    const bool is_pred = d < 4;
    const int tid = threadIdx.x;
    const int lane = tid & 63, wid = tid >> 6;

    // ---- P0: values -> 64-bit sort keys (value desc, idx asc) ----
    for (int p = tid; p < N_PIX; p += 256) {
        float v;
        if (is_pred) {
            float l0 = logits[smp * 2 * N_PIX + p];
            float l1 = logits[smp * 2 * N_PIX + N_PIX + p];
            float m = fmaxf(l0, l1);
            float e0 = expf(l0 - m), e1 = expf(l1 - m);
            v = e1 / (e0 + e1);
        } else {
            v = target[smp * N_PIX + p];
        }
        s_key[p] = ((unsigned long long)fmap_desc(v) << 32) | (unsigned)p;
    }
    __syncthreads();

    // ---- P1: bitonic sort 4096 keys ascending ----
    for (unsigned k = 2; k <= N_PIX; k <<= 1) {
        for (unsigned j = k >> 1; j > 0; j >>= 1) {
            for (unsigned idx = tid; idx < N_PIX; idx += 256) {
                unsigned ixj = idx ^ j;
                if (ixj > idx) {
                    unsigned long long a = s_key[idx], b = s_key[ixj];
                    bool up = ((idx & k) == 0);
                    if ((a > b) == up) { s_key[idx] = b; s_key[ixj] = a; }
                }
            }
            __syncthreads();
        }
    }
    for (int t = tid; t < N_PIX; t += 256) {
        unsigned long long kk = s_key[t];
        int p = (int)(kk & 0xFFFFFFFFull);
        s_order[t] = (unsigned short)p;
        s_rank[p] = (unsigned short)t;
        s_vrk[t] = funmap_desc((unsigned)(kk >> 32));
        s_parent[t] = (unsigned short)t;
    }
    __syncthreads();

    // ---- P2: steepest-ascent forest + pointer jumping -> peak label ----
    for (int p = tid; p < N_PIX; p += 256) {
        int r = p >> 6, c = p & 63;
        int best = s_rank[p], bj = p;
        if (r > 0)  { int t2 = s_rank[p - HW]; if (t2 < best) { best = t2; bj = p - HW; } }
        if (r < 63) { int t2 = s_rank[p + HW]; if (t2 < best) { best = t2; bj = p + HW; } }
        if (c > 0)  { int t2 = s_rank[p - 1];  if (t2 < best) { best = t2; bj = p - 1; } }
        if (c < 63) { int t2 = s_rank[p + 1];  if (t2 < best) { best = t2; bj = p + 1; } }
        s_plab[p] = (unsigned short)bj;
    }
    __syncthreads();
    for (int it = 0; it < 12; ++it) {  // paths up to 4095 -> 12 doubling rounds
        for (int p = tid; p < N_PIX; p += 256) {
            unsigned short a = s_plab[p];
            s_plab[p] = s_plab[a];
        }
        __syncthreads();
    }
    for (int p = tid; p < N_PIX; p += 256) s_plab[p] = s_rank[s_plab[p]];
    if (tid == 0) s_cnt = 0;
    __syncthreads();

    // ---- P4: chunked elder-rule union-find ----
    // Per chunk of 256 ranks: (a) parallel: gather added-neighbor basin labels,
    // dedup, resolve snapshot roots read-only; drop events whose labels share one
    // root (can never union). (b) ballot-compact in rank order. (c) serial: finds
    // start from snapshot roots -> only traverse intra-chunk unions (0-2 hops).
    for (int ch = 0; ch < NCHUNK; ++ch) {
        const int t = ch * CHUNK + tid;
        const int i = s_order[t];
        const int r = i >> 6, c = i & 63;
        unsigned short labs[4]; int nl = 0;
        if (r > 0  && (int)s_rank[i - HW] < t) labs[nl++] = s_plab[i - HW];
        if (r < 63 && (int)s_rank[i + HW] < t) labs[nl++] = s_plab[i + HW];
        if (c > 0  && (int)s_rank[i - 1]  < t) labs[nl++] = s_plab[i - 1];
        if (c < 63 && (int)s_rank[i + 1]  < t) labs[nl++] = s_plab[i + 1];
        // dedup labels
        unsigned short ul[4]; int nu = 0;
        for (int q = 0; q < nl; ++q) {
            bool dup = false;
            for (int w = 0; w < nu; ++w) dup |= (ul[w] == labs[q]);
            if (!dup) ul[nu++] = labs[q];
        }
        // resolve snapshot roots (read-only walk; serial writer idle)
        unsigned short rt[4]; int nr = 0;
        for (int q = 0; q < nu; ++q) {
            int x = ul[q];
            while (true) { int a = s_parent[x]; if (a == x) break; x = a; }
            bool dup = false;
            for (int w = 0; w < nr; ++w) dup |= (rt[w] == (unsigned short)x);
            if (!dup) rt[nr++] = (unsigned short)x;
        }
        const bool ev = (nr >= 2);
        unsigned long long m = __ballot(ev);
        if (lane == 0) s_wc[wid] = __popcll(m);
        __syncthreads();
        int base = 0;
        for (int w = 0; w < wid; ++w) base += s_wc[w];
        if (ev) {
            int pos = base + __popcll(m & ((1ull << lane) - 1ull));
            ushort4 rec;
            rec.x = rt[0]; rec.y = rt[1];
            rec.z = (nr > 2) ? rt[2] : (unsigned short)0xFFFF;
            rec.w = (nr > 3) ? rt[3] : (unsigned short)0xFFFF;
            s_hint[pos] = rec;
            s_evr[pos] = (unsigned short)t;
        }
        __syncthreads();
        if (tid == 0) {
            const int nev = s_wc[0] + s_wc[1] + s_wc[2] + s_wc[3];
            int cnt = s_cnt;
            for (int e = 0; e < nev; ++e) {
                ushort4 R = s_hint[e];
                const int te = s_evr[e];
                unsigned short hs[4] = { R.x, R.y, R.z, R.w };
                int rts[4]; int nrr = 0;
                #pragma unroll
                for (int q = 0; q < 4; ++q) {
                    if (hs[q] == 0xFFFF) continue;
                    int x = hs[q];
                    while (true) {           // path-halving find (serial: writes ok)
                        int a = s_parent[x];
                        if (a == x) break;
                        int b = s_parent[a];
                        s_parent[x] = (unsigned short)b;
                        x = b;
                    }
                    s_parent[hs[q]] = (unsigned short)x;  // compress snapshot root
                    bool dup = false;
                    for (int w = 0; w < nrr; ++w) dup |= (rts[w] == x);
                    if (!dup) rts[nrr++] = x;
                }
                if (nrr >= 2) {
                    int elder = rts[0];
                    for (int w = 1; w < nrr; ++w) if (rts[w] < elder) elder = rts[w];
                    const float vd = s_vrk[te];
                    for (int w = 0; w < nrr; ++w) {
                        int rr = rts[w];
                        if (rr == elder) continue;
                        s_parent[rr] = (unsigned short)elder;
                        if (s_vrk[rr] > vd)   // strictly positive persistence only
                            s_bars[cnt++] = ((unsigned)rr << 16) | (unsigned)te;
                    }
                }
            }
            s_cnt = cnt;
        }
        __syncthreads();
    }

    // essential bar: global max born, dies at global min
    if (tid == 0) {
        if (s_vrk[0] > s_vrk[N_PIX - 1])
            s_bars[s_cnt++] = (0u << 16) | (unsigned)(N_PIX - 1);
    }
    __syncthreads();

    // ---- P5: sort bars by persistence desc (adaptive-width bitonic) ----
    const int bc = s_cnt;
    int NS = 64; while (NS < bc) NS <<= 1;   // pow2 >= bc, <= 2048
    unsigned long long* s_bk = s_key;        // sort keys dead, reuse
    for (int t = tid; t < NS; t += 256) {
        unsigned long long k;
        if (t < bc) {
            unsigned bb = s_bars[t];
            float pers = s_vrk[bb >> 16] - s_vrk[bb & 0xFFFFu];  // >= 0
            k = ((unsigned long long)(~__float_as_uint(pers)) << 32) | bb;
        } else k = ~0ull;
        s_bk[t] = k;
    }
    __syncthreads();
    for (int k = 2; k <= NS; k <<= 1) {
        for (int j = k >> 1; j > 0; j >>= 1) {
            for (int idx = tid; idx < NS; idx += 256) {
                int ixj = idx ^ j;
                if (ixj > idx) {
                    unsigned long long a = s_bk[idx], b = s_bk[ixj];
                    bool up = ((idx & k) == 0);
                    if ((a > b) == up) { s_bk[idx] = b; s_bk[ixj] = a; }
                }
            }
            __syncthreads();
        }
    }

    // ---- P6: write (birth, death) values + count ----
    float* B = wsB + d * 2 * NBARS;
    float* D = B + NBARS;
    for (int t = tid; t < NBARS; t += 256) {
        float b = 0.0f, dd = 0.0f;
        if (t < bc) {
            unsigned bb = (unsigned)(s_bk[t] & 0xFFFFFFFFull);
            b = s_vrk[bb >> 16];
            dd = s_vrk[bb & 0xFFFFu];
        }
        B[t] = b; D[t] = dd;
    }
    if (tid == 0) wsK[d] = bc;
}

extern "C" __global__ void __launch_bounds__(256)
betti_loss_kernel(const float* __restrict__ wsB, const int* __restrict__ wsK,
                  float* __restrict__ out) {
    const int s = blockIdx.x;
    const float* B1 = wsB + s * 2 * NBARS;
    const float* D1 = B1 + NBARS;
    const float* B2 = wsB + (4 + s) * 2 * NBARS;
    const float* D2 = B2 + NBARS;
    const int K1 = wsK[s], K2 = wsK[4 + s];
    const int mn = min(K1, K2);
    const int tid = threadIdx.x;

    float acc = 0.0f;
    for (int t = tid; t < NBARS; t += 256) {
        if (t < mn) {
            float db = B1[t] - B2[t];
            float dd = D1[t] - D2[t];
            acc += db * db + dd * dd;
        } else {
            if (t < K1) { float e = B1[t] - D1[t]; acc += 0.5f * e * e; }
            if (t < K2) { float e = B2[t] - D2[t]; acc += 0.5f * e * e; }
        }
    }
    for (int off = 32; off > 0; off >>= 1) acc += __shfl_down(acc, off);
    __shared__ float red[4];
    const int wid = tid >> 6, lane = tid & 63;
    if (lane == 0) red[wid] = acc;
    __syncthreads();
    if (tid == 0) {
        float tsum = red[0] + red[1] + red[2] + red[3];
        atomicAdd(out, 0.25f * tsum);
    }
}

extern "C" void kernel_launch(void* const* d_in, const int* in_sizes, int n_in,
                              void* d_out, int out_size, void* d_ws, size_t ws_size,
                              hipStream_t stream) {
    const float* logits = (const float*)d_in[0];   // (4,2,64,64) f32
    const float* target = (const float*)d_in[1];   // (4,64,64) f32
    float* wsB = (float*)d_ws;                     // 8 diagrams * 2 * 2048 floats
    int* wsK = (int*)((char*)d_ws + (size_t)8 * 2 * NBARS * sizeof(float));

    hipMemsetAsync(d_out, 0, sizeof(float), stream);
    hipLaunchKernelGGL(ph0_diagram_kernel, dim3(8), dim3(256), 0, stream,
                       logits, target, wsB, wsK);
    hipLaunchKernelGGL(betti_loss_kernel, dim3(4), dim3(256), 0, stream,
                       wsB, wsK, (float*)d_out);
}

// Round 4
// 826.259 us; speedup vs baseline: 4.0464x; 1.3796x over previous
//
#include <hip/hip_runtime.h>

#define N_PIX 4096
#define HW 64
#define NBARS 2048
#define CINF 0xFFFFFFFFu

__device__ __forceinline__ unsigned fmap_desc(float f) {
    unsigned u = __float_as_uint(f);
    unsigned m = u ^ (((unsigned)((int)u >> 31)) | 0x80000000u); // ascending map
    return ~m;                                                   // descending
}
__device__ __forceinline__ float funmap_desc(unsigned k) {
    unsigned m = ~k;
    unsigned u = (m & 0x80000000u) ? (m ^ 0x80000000u) : ~m;
    return __uint_as_float(u);
}

extern "C" __global__ void __launch_bounds__(256)
ph0_kernel(const float* __restrict__ logits, const float* __restrict__ target,
           float* __restrict__ wsB, int* __restrict__ wsK) {
    __shared__ unsigned long long s_key[N_PIX];   // 32KB: sortkeys -> MST edges -> bar keys
    __shared__ float s_vrk[N_PIX];                // 16KB: value by rank
    __shared__ unsigned int s_cmin[N_PIX];        // 16KB: Boruvka per-comp min key / Kruskal hints
    __shared__ unsigned short s_rank[N_PIX];      // 8KB: pixel->rank (pred) / CCL labels (target)
    __shared__ unsigned short s_nx[N_PIX];        // 8KB: Boruvka contraction pointers
    __shared__ unsigned short s_plab[N_PIX];      // 8KB: pixel->basin peak rank / is1 (target)
    __shared__ unsigned short s_parent[N_PIX];    // 8KB: comp[] then Kruskal union-find
    __shared__ unsigned int s_bars[NBARS];        // 8KB
    __shared__ int s_nm, s_cnt, s_any, s_jany;

    const int d = blockIdx.x;        // 0..3 pred, 4..7 target
    const int smp = d & 3;
    const int tid = threadIdx.x;

    if (d < 4) {
        // =========================== PRED ===========================
        // ---- P0: softmax fg channel -> sort keys (value desc, idx asc) ----
        for (int p = tid; p < N_PIX; p += 256) {
            float l0 = logits[smp * 2 * N_PIX + p];
            float l1 = logits[smp * 2 * N_PIX + N_PIX + p];
            float m = fmaxf(l0, l1);
            float e0 = expf(l0 - m), e1 = expf(l1 - m);
            float v = e1 / (e0 + e1);
            s_key[p] = ((unsigned long long)fmap_desc(v) << 32) | (unsigned)p;
        }
        __syncthreads();
        // ---- P1: bitonic sort 4096 ----
        for (unsigned k = 2; k <= N_PIX; k <<= 1)
            for (unsigned j = k >> 1; j > 0; j >>= 1) {
                for (unsigned idx = tid; idx < N_PIX; idx += 256) {
                    unsigned ixj = idx ^ j;
                    if (ixj > idx) {
                        unsigned long long a = s_key[idx], b = s_key[ixj];
                        bool up = ((idx & k) == 0);
                        if ((a > b) == up) { s_key[idx] = b; s_key[ixj] = a; }
                    }
                }
                __syncthreads();
            }
        for (int t = tid; t < N_PIX; t += 256) {
            unsigned long long kk = s_key[t];
            int p = (int)(kk & 0xFFFFFFFFull);
            s_rank[p] = (unsigned short)t;
            s_vrk[t] = funmap_desc((unsigned)(kk >> 32));
            s_parent[t] = (unsigned short)t;   // comp init
            s_cmin[t] = CINF;
        }
        if (tid == 0) { s_nm = 0; s_cnt = 0; }
        __syncthreads();
        // ---- P2: steepest-ascent basins + pointer jumping ----
        for (int p = tid; p < N_PIX; p += 256) {
            int r = p >> 6, c = p & 63;
            int best = s_rank[p], bj = p;
            if (r > 0)  { int t2 = s_rank[p - HW]; if (t2 < best) { best = t2; bj = p - HW; } }
            if (r < 63) { int t2 = s_rank[p + HW]; if (t2 < best) { best = t2; bj = p + HW; } }
            if (c > 0)  { int t2 = s_rank[p - 1];  if (t2 < best) { best = t2; bj = p - 1; } }
            if (c < 63) { int t2 = s_rank[p + 1];  if (t2 < best) { best = t2; bj = p + 1; } }
            s_plab[p] = (unsigned short)bj;
        }
        __syncthreads();
        for (int it = 0; it < 12; ++it) {
            for (int p = tid; p < N_PIX; p += 256) {
                unsigned short a = s_plab[p];
                s_plab[p] = s_plab[a];
            }
            __syncthreads();
        }
        for (int p = tid; p < N_PIX; p += 256) s_plab[p] = s_rank[s_plab[p]];
        __syncthreads();

        // ---- P3: Boruvka MST over basins (edge weight = rank of later pixel) ----
        for (int round = 0; round < 12; ++round) {
            if (tid == 0) s_any = 0;
            __syncthreads();
            // scan: per pixel, forward adjacencies (right, down)
            for (int p = tid; p < N_PIX; p += 256) {
                int r = p >> 6, c = p & 63;
                int a = s_plab[p];
                int rp = s_rank[p];
                if (c < 63) {
                    int b = s_plab[p + 1];
                    if (b != a) {
                        int ca = s_parent[a], cb = s_parent[b];
                        if (ca != cb) {
                            unsigned w = (unsigned)max(rp, (int)s_rank[p + 1]);
                            unsigned key = (w << 13) | ((unsigned)p << 1);
                            atomicMin(&s_cmin[ca], key);
                            atomicMin(&s_cmin[cb], key);
                        }
                    }
                }
                if (r < 63) {
                    int b = s_plab[p + HW];
                    if (b != a) {
                        int ca = s_parent[a], cb = s_parent[b];
                        if (ca != cb) {
                            unsigned w = (unsigned)max(rp, (int)s_rank[p + HW]);
                            unsigned key = (w << 13) | (((unsigned)p << 1) | 1u);
                            atomicMin(&s_cmin[ca], key);
                            atomicMin(&s_cmin[cb], key);
                        }
                    }
                }
            }
            __syncthreads();
            // link + emit (dedup: same-key means same edge; unique keys via id bits)
            for (int r = tid; r < N_PIX; r += 256) {
                unsigned k = s_cmin[r];
                unsigned short nxv = (unsigned short)r;
                if (k != CINF) {
                    s_any = 1;
                    unsigned id = k & 0x1FFFu;
                    int p = (int)(id >> 1);
                    int q = p + ((id & 1u) ? HW : 1);
                    int a = s_plab[p], b = s_plab[q];
                    int ca = s_parent[a], cb = s_parent[b];
                    int partner = (ca == r) ? cb : ca;
                    nxv = (unsigned short)partner;
                    if (s_cmin[partner] != k || r < partner) {
                        int e = atomicAdd(&s_nm, 1);
                        unsigned w = k >> 13;
                        s_key[e] = ((unsigned long long)w << 24) |
                                   ((unsigned long long)a << 12) | (unsigned long long)b;
                    }
                }
                s_nx[r] = nxv;
            }
            __syncthreads();
            // resolve 2-cycles (read flags, then write)
            bool self_[16];
            {
                int q0 = 0;
                for (int r = tid; r < N_PIX; r += 256) {
                    int pr = s_nx[r];
                    self_[q0++] = (s_nx[pr] == r && r < pr);
                }
            }
            __syncthreads();
            {
                int q0 = 0;
                for (int r = tid; r < N_PIX; r += 256)
                    if (self_[q0++]) s_nx[r] = (unsigned short)r;
            }
            __syncthreads();
            // adaptive pointer jumping
            for (int it = 0; it < 12; ++it) {
                if (tid == 0) s_jany = 0;
                __syncthreads();
                bool ch = false;
                for (int r = tid; r < N_PIX; r += 256) {
                    unsigned short a1 = s_nx[r];
                    unsigned short b1 = s_nx[a1];
                    if (b1 != a1) { s_nx[r] = b1; ch = true; }
                }
                if (ch) s_jany = 1;
                __syncthreads();
                int jv = s_jany;
                __syncthreads();
                if (!jv) break;
            }
            // comp update + cmin reset
            for (int t = tid; t < N_PIX; t += 256) {
                s_parent[t] = s_nx[s_parent[t]];
                s_cmin[t] = CINF;
            }
            __syncthreads();
            int av = s_any;
            __syncthreads();
            if (!av) break;
        }

        // ---- P4: sort MST edges by weight (ascending) ----
        const int nm = s_nm;
        int NSm = 256; while (NSm < nm) NSm <<= 1;
        for (int t = tid; t < NSm; t += 256) if (t >= nm) s_key[t] = ~0ull;
        __syncthreads();
        for (int k = 2; k <= NSm; k <<= 1)
            for (int j = k >> 1; j > 0; j >>= 1) {
                for (int idx = tid; idx < NSm; idx += 256) {
                    int ixj = idx ^ j;
                    if (ixj > idx) {
                        unsigned long long a = s_key[idx], b = s_key[ixj];
                        bool up = ((idx & k) == 0);
                        if ((a > b) == up) { s_key[idx] = b; s_key[ixj] = a; }
                    }
                }
                __syncthreads();
            }

        // ---- P5: Kruskal elder-rule pairing over ~820 edges (hint-batched) ----
        for (int t = tid; t < N_PIX; t += 256) s_parent[t] = (unsigned short)t;
        if (tid == 0) s_cnt = 0;
        __syncthreads();
        for (int e0 = 0; e0 < nm; e0 += 256) {
            int e = e0 + tid;
            if (e < nm) {
                unsigned long long E = s_key[e];
                int a = (int)((E >> 12) & 0xFFFull), b = (int)(E & 0xFFFull);
                int x = a, px = s_parent[x];
                while (px != x) { x = px; px = s_parent[x]; }
                s_parent[a] = (unsigned short)x;          // benign compression
                int y = b, py = s_parent[y];
                while (py != y) { y = py; py = s_parent[y]; }
                s_parent[b] = (unsigned short)y;
                s_cmin[e] = ((unsigned)x << 16) | (unsigned)y;
            }
            __syncthreads();
            if (tid == 0) {
                int cnt = s_cnt;
                int eend = min(nm, e0 + 256);
                for (int ee = e0; ee < eend; ++ee) {
                    unsigned h = s_cmin[ee];
                    unsigned long long E = s_key[ee];
                    int w = (int)(E >> 24);
                    int ra = (int)(h >> 16), rb = (int)(h & 0xFFFFu);
                    while (true) { int pa = s_parent[ra]; if (pa == ra) break;
                                   int ga = s_parent[pa]; s_parent[ra] = (unsigned short)ga; ra = ga; }
                    while (true) { int pb = s_parent[rb]; if (pb == rb) break;
                                   int gb = s_parent[pb]; s_parent[rb] = (unsigned short)gb; rb = gb; }
                    if (ra == rb) continue;
                    int elder = min(ra, rb), young = max(ra, rb);
                    s_parent[young] = (unsigned short)elder;
                    if (s_vrk[young] > s_vrk[w])
                        s_bars[cnt++] = ((unsigned)young << 16) | (unsigned)w;
                }
                s_cnt = cnt;
            }
            __syncthreads();
        }
        if (tid == 0) {
            if (s_vrk[0] > s_vrk[N_PIX - 1])
                s_bars[s_cnt++] = (0u << 16) | (unsigned)(N_PIX - 1);
        }
        __syncthreads();

        // ---- P6: sort bars by persistence desc + write ----
        const int bc = s_cnt;
        int NS = 64; while (NS < bc) NS <<= 1;
        for (int t = tid; t < NS; t += 256) {
            unsigned long long k;
            if (t < bc) {
                unsigned bb = s_bars[t];
                float pers = s_vrk[bb >> 16] - s_vrk[bb & 0xFFFFu];
                k = ((unsigned long long)(~__float_as_uint(pers)) << 32) | bb;
            } else k = ~0ull;
            s_key[t] = k;
        }
        __syncthreads();
        for (int k = 2; k <= NS; k <<= 1)
            for (int j = k >> 1; j > 0; j >>= 1) {
                for (int idx = tid; idx < NS; idx += 256) {
                    int ixj = idx ^ j;
                    if (ixj > idx) {
                        unsigned long long a = s_key[idx], b = s_key[ixj];
                        bool up = ((idx & k) == 0);
                        if ((a > b) == up) { s_key[idx] = b; s_key[ixj] = a; }
                    }
                }
                __syncthreads();
            }
        float* B = wsB + d * 2 * NBARS;
        float* D = B + NBARS;
        for (int t = tid; t < NBARS; t += 256) {
            float b = 0.0f, dd = 0.0f;
            if (t < bc) {
                unsigned bb = (unsigned)(s_key[t] & 0xFFFFFFFFull);
                b = s_vrk[bb >> 16];
                dd = s_vrk[bb & 0xFFFFu];
            }
            B[t] = b; D[t] = dd;
        }
        if (tid == 0) wsK[d] = bc;
    } else {
        // ========================== TARGET ==========================
        // Binary image: every positive bar is (1,0); count = #components of 1s
        // (0 if image has no 0s or no 1s).
        const float* tg = target + smp * N_PIX;
        for (int p = tid; p < N_PIX; p += 256) {
            bool one = tg[p] > 0.5f;
            s_plab[p] = one ? 1 : 0;
            s_rank[p] = one ? (unsigned short)p : (unsigned short)0xFFFF;
        }
        if (tid == 0) s_nm = 0;
        __syncthreads();
        {
            int c1 = 0;
            for (int p = tid; p < N_PIX; p += 256) c1 += s_plab[p];
            for (int off = 32; off > 0; off >>= 1) c1 += __shfl_down(c1, off);
            if ((tid & 63) == 0) atomicAdd(&s_nm, c1);
        }
        __syncthreads();
        const int n1 = s_nm;
        // CCL: min-label propagation + double pointer-jump; fixpoint == correct labels
        for (int round = 0; round < 128; ++round) {
            if (tid == 0) s_any = 0;
            __syncthreads();
            bool ch = false;
            for (int p = tid; p < N_PIX; p += 256) {
                if (!s_plab[p]) continue;
                int r = p >> 6, c = p & 63;
                int m = s_rank[p];
                if (r > 0  && s_plab[p - HW]) m = min(m, (int)s_rank[p - HW]);
                if (r < 63 && s_plab[p + HW]) m = min(m, (int)s_rank[p + HW]);
                if (c > 0  && s_plab[p - 1])  m = min(m, (int)s_rank[p - 1]);
                if (c < 63 && s_plab[p + 1])  m = min(m, (int)s_rank[p + 1]);
                int m2 = s_rank[m];
                int m3 = s_rank[m2];
                if (m3 < (int)s_rank[p]) { s_rank[p] = (unsigned short)m3; ch = true; }
            }
            if (ch) s_any = 1;
            __syncthreads();
            int av = s_any;
            __syncthreads();
            if (!av) break;
        }
        {
            int rc = 0;
            for (int p = tid; p < N_PIX; p += 256)
                if (s_plab[p] && s_rank[p] == (unsigned short)p) rc++;
            for (int off = 32; off > 0; off >>= 1) rc += __shfl_down(rc, off);
            if (tid == 0) s_cnt = 0;
            __syncthreads();
            if ((tid & 63) == 0) atomicAdd(&s_cnt, rc);
            __syncthreads();
            if (tid == 0) wsK[d] = (n1 == N_PIX) ? 0 : s_cnt;
        }
    }
}

extern "C" __global__ void __launch_bounds__(256)
betti_loss_kernel(const float* __restrict__ wsB, const int* __restrict__ wsK,
                  float* __restrict__ out) {
    const int s = blockIdx.x;
    const int tid = threadIdx.x;
    const float* B1 = wsB + s * 2 * NBARS;
    const float* D1 = B1 + NBARS;
    const int K1 = wsK[s], K2 = wsK[4 + s];
    const int mn = min(K1, K2);

    float acc = 0.0f;
    for (int t = tid; t < K1; t += 256) {
        float b = B1[t], dd = D1[t];
        if (t < mn) { float db = b - 1.0f; acc += db * db + dd * dd; } // target bar = (1,0)
        else        { float e = b - dd;    acc += 0.5f * e * e; }
    }
    if (tid == 0 && K2 > mn) acc += 0.5f * (float)(K2 - mn);           // unmatched (1,0) bars
    for (int off = 32; off > 0; off >>= 1) acc += __shfl_down(acc, off);
    __shared__ float red[4];
    const int wid = tid >> 6, lane = tid & 63;
    if (lane == 0) red[wid] = acc;
    __syncthreads();
    if (tid == 0) atomicAdd(out, 0.25f * (red[0] + red[1] + red[2] + red[3]));
}

extern "C" void kernel_launch(void* const* d_in, const int* in_sizes, int n_in,
                              void* d_out, int out_size, void* d_ws, size_t ws_size,
                              hipStream_t stream) {
    const float* logits = (const float*)d_in[0];   // (4,2,64,64) f32
    const float* target = (const float*)d_in[1];   // (4,64,64) f32
    float* wsB = (float*)d_ws;                     // 4 pred diagrams * 2 * 2048 floats
    int* wsK = (int*)((char*)d_ws + (size_t)4 * 2 * NBARS * sizeof(float));

    hipMemsetAsync(d_out, 0, sizeof(float), stream);
    hipLaunchKernelGGL(ph0_kernel, dim3(8), dim3(256), 0, stream,
                       logits, target, wsB, wsK);
    hipLaunchKernelGGL(betti_loss_kernel, dim3(4), dim3(256), 0, stream,
                       wsB, wsK, (float*)d_out);
}

// Round 5
// 176.787 us; speedup vs baseline: 18.9119x; 4.6738x over previous
//
#include <hip/hip_runtime.h>

#define N_PIX 4096
#define HW 64
#define NBARS 2048
#define TINF 0xFFFFFFFFu
#define NT 1024

__device__ __forceinline__ unsigned fmap_desc(float f) {
    unsigned u = __float_as_uint(f);
    unsigned m = u ^ (((unsigned)((int)u >> 31)) | 0x80000000u); // ascending map
    return ~m;                                                   // descending
}
__device__ __forceinline__ float funmap_desc(unsigned k) {
    unsigned m = ~k;
    unsigned u = (m & 0x80000000u) ? (m ^ 0x80000000u) : ~m;
    return __uint_as_float(u);
}

// Lock-free triplet merge: node ids are ranks (0 = eldest). T[x] = (s<<12)|v:
// component of x merges at saddle-rank s into chain of v (v < x). TINF = alive.
// Invariants: links point to strictly smaller rank (acyclic chains); a node's
// s only decreases (CAS guarded); w >= ra at every link.
__device__ __forceinline__ int tm_rep(unsigned* T, int u, int w) {
    while (true) {
        unsigned t = *(volatile unsigned*)&T[u];
        if (t == TINF) break;
        int s = (int)(t >> 12);
        if (s > w) break;
        u = (int)(t & 0xFFFu);
    }
    return u;
}

__device__ void tm_merge(unsigned* T, int a, int b, int w) {
    for (int guard = 0; guard < (1 << 20); ++guard) {
        int ra = tm_rep(T, a, w);
        int rb = tm_rep(T, b, w);
        if (ra == rb) return;
        if (ra < rb) { int t = ra; ra = rb; rb = t; }   // ra = younger (larger rank)
        unsigned old = *(volatile unsigned*)&T[ra];
        if (old != TINF && (int)(old >> 12) <= w) continue;  // stale rep; re-walk
        unsigned nv = ((unsigned)w << 12) | (unsigned)rb;
        if (atomicCAS(&T[ra], old, nv) != old) continue;      // lost race; retry
        if (old == TINF) return;
        // displaced link (ra died at old.s into old.v) re-hangs off rb's chain
        a = rb; b = (int)(old & 0xFFFu); w = (int)(old >> 12);
    }
}

extern "C" __global__ void __launch_bounds__(NT)
ph0_kernel(const float* __restrict__ logits, const float* __restrict__ target,
           float* __restrict__ wsB, int* __restrict__ wsK) {
    __shared__ unsigned long long s_key[N_PIX];   // 32KB: sort keys -> bar sort keys
    __shared__ float s_vrk[N_PIX];                // 16KB: value by rank
    __shared__ unsigned short s_rank[N_PIX];      // 8KB: pixel->rank | target labels
    __shared__ unsigned s_T[N_PIX];               // 16KB: triplet slots | target mask
    __shared__ unsigned s_bars[NBARS];            // 8KB: (young<<16)|death_rank
    __shared__ int s_nm, s_cnt, s_any;

    const int d = blockIdx.x;        // 0..3 pred, 4..7 target
    const int smp = d & 3;
    const int tid = threadIdx.x;

    if (d < 4) {
        // =========================== PRED ===========================
        // ---- P0: softmax fg channel -> sort keys (value desc, idx asc) ----
        for (int p = tid; p < N_PIX; p += NT) {
            float l0 = logits[smp * 2 * N_PIX + p];
            float l1 = logits[smp * 2 * N_PIX + N_PIX + p];
            float m = fmaxf(l0, l1);
            float e0 = expf(l0 - m), e1 = expf(l1 - m);
            float v = e1 / (e0 + e1);
            s_key[p] = ((unsigned long long)fmap_desc(v) << 32) | (unsigned)p;
        }
        __syncthreads();
        // ---- P1: bitonic sort 4096 keys ascending ----
        for (unsigned k = 2; k <= N_PIX; k <<= 1)
            for (unsigned j = k >> 1; j > 0; j >>= 1) {
                for (unsigned idx = tid; idx < N_PIX; idx += NT) {
                    unsigned ixj = idx ^ j;
                    if (ixj > idx) {
                        unsigned long long a = s_key[idx], b = s_key[ixj];
                        bool up = ((idx & k) == 0);
                        if ((a > b) == up) { s_key[idx] = b; s_key[ixj] = a; }
                    }
                }
                __syncthreads();
            }
        for (int t = tid; t < N_PIX; t += NT) {
            unsigned long long kk = s_key[t];
            int p = (int)(kk & 0xFFFFFFFFull);
            s_rank[p] = (unsigned short)t;
            s_vrk[t] = funmap_desc((unsigned)(kk >> 32));
            s_T[t] = TINF;
        }
        if (tid == 0) s_cnt = 0;
        __syncthreads();

        // ---- P2: lock-free triplet merge over all 8064 pixel adjacencies ----
        // edge (p,q): both components exist from rank max(rank_p, rank_q) on;
        // that max IS the death pixel's rank (exactly the reference's merge pt).
        for (int p = tid; p < N_PIX; p += NT) {
            int r = p >> 6, c = p & 63;
            int rp = s_rank[p];
            if (c < 63) {
                int rq = s_rank[p + 1];
                tm_merge(s_T, rp, rq, max(rp, rq));
            }
            if (r < 63) {
                int rq = s_rank[p + HW];
                tm_merge(s_T, rp, rq, max(rp, rq));
            }
        }
        __syncthreads();

        // ---- P3: collect positive-persistence bars ----
        for (int t = tid; t < N_PIX; t += NT) {
            if (t == 0) continue;                 // eldest root: essential bar below
            unsigned tv = s_T[t];
            int s = (int)(tv >> 12);
            if (s_vrk[t] > s_vrk[s]) {
                int e = atomicAdd(&s_cnt, 1);
                s_bars[e] = ((unsigned)t << 16) | (unsigned)s;
            }
        }
        __syncthreads();
        if (tid == 0) {
            if (s_vrk[0] > s_vrk[N_PIX - 1])
                s_bars[s_cnt++] = (0u << 16) | (unsigned)(N_PIX - 1);
        }
        __syncthreads();

        // ---- P4: sort bars by persistence desc (adaptive-width bitonic) ----
        const int bc = s_cnt;
        int NS = 64; while (NS < bc) NS <<= 1;
        for (int t = tid; t < NS; t += NT) {
            unsigned long long k;
            if (t < bc) {
                unsigned bb = s_bars[t];
                float pers = s_vrk[bb >> 16] - s_vrk[bb & 0xFFFFu];
                k = ((unsigned long long)(~__float_as_uint(pers)) << 32) | bb;
            } else k = ~0ull;
            s_key[t] = k;
        }
        __syncthreads();
        for (int k = 2; k <= NS; k <<= 1)
            for (int j = k >> 1; j > 0; j >>= 1) {
                for (int idx = tid; idx < NS; idx += NT) {
                    int ixj = idx ^ j;
                    if (ixj > idx) {
                        unsigned long long a = s_key[idx], b = s_key[ixj];
                        bool up = ((idx & k) == 0);
                        if ((a > b) == up) { s_key[idx] = b; s_key[ixj] = a; }
                    }
                }
                __syncthreads();
            }

        // ---- P5: write (birth, death) values + count ----
        float* B = wsB + d * 2 * NBARS;
        float* D = B + NBARS;
        for (int t = tid; t < NBARS; t += NT) {
            float b = 0.0f, dd = 0.0f;
            if (t < bc) {
                unsigned bb = (unsigned)(s_key[t] & 0xFFFFFFFFull);
                b = s_vrk[bb >> 16];
                dd = s_vrk[bb & 0xFFFFu];
            }
            B[t] = b; D[t] = dd;
        }
        if (tid == 0) wsK[d] = bc;
    } else {
        // ========================== TARGET ==========================
        // Binary image: every positive bar is (1,0); count = #components of 1s
        // (0 if the image has no 0s or no 1s).
        const float* tg = target + smp * N_PIX;
        unsigned short* s_one = (unsigned short*)s_T;
        unsigned short* s_lab = s_rank;
        for (int p = tid; p < N_PIX; p += NT) {
            bool one = tg[p] > 0.5f;
            s_one[p] = one ? 1 : 0;
            s_lab[p] = one ? (unsigned short)p : (unsigned short)0xFFFF;
        }
        if (tid == 0) { s_nm = 0; s_cnt = 0; }
        __syncthreads();
        {
            int c1 = 0;
            for (int p = tid; p < N_PIX; p += NT) c1 += s_one[p];
            for (int off = 32; off > 0; off >>= 1) c1 += __shfl_down(c1, off);
            if ((tid & 63) == 0) atomicAdd(&s_nm, c1);
        }
        __syncthreads();
        const int n1 = s_nm;
        // CCL: min-label propagation + double pointer-jump; fixpoint = labels
        for (int round = 0; round < 128; ++round) {
            if (tid == 0) s_any = 0;
            __syncthreads();
            bool ch = false;
            for (int p = tid; p < N_PIX; p += NT) {
                if (!s_one[p]) continue;
                int r = p >> 6, c = p & 63;
                int m = s_lab[p];
                if (r > 0  && s_one[p - HW]) m = min(m, (int)s_lab[p - HW]);
                if (r < 63 && s_one[p + HW]) m = min(m, (int)s_lab[p + HW]);
                if (c > 0  && s_one[p - 1])  m = min(m, (int)s_lab[p - 1]);
                if (c < 63 && s_one[p + 1])  m = min(m, (int)s_lab[p + 1]);
                int m3 = s_lab[s_lab[m]];
                if (m3 < (int)s_lab[p]) { s_lab[p] = (unsigned short)m3; ch = true; }
            }
            if (ch) s_any = 1;
            __syncthreads();
            int av = s_any;
            __syncthreads();
            if (!av) break;
        }
        {
            int rc = 0;
            for (int p = tid; p < N_PIX; p += NT)
                if (s_one[p] && s_lab[p] == (unsigned short)p) rc++;
            for (int off = 32; off > 0; off >>= 1) rc += __shfl_down(rc, off);
            if ((tid & 63) == 0) atomicAdd(&s_cnt, rc);
            __syncthreads();
            if (tid == 0) wsK[d] = (n1 == N_PIX) ? 0 : s_cnt;
        }
    }
}

extern "C" __global__ void __launch_bounds__(256)
betti_loss_kernel(const float* __restrict__ wsB, const int* __restrict__ wsK,
                  float* __restrict__ out) {
    const int s = blockIdx.x;
    const int tid = threadIdx.x;
    const float* B1 = wsB + s * 2 * NBARS;
    const float* D1 = B1 + NBARS;
    const int K1 = wsK[s], K2 = wsK[4 + s];
    const int mn = min(K1, K2);

    float acc = 0.0f;
    for (int t = tid; t < K1; t += 256) {
        float b = B1[t], dd = D1[t];
        if (t < mn) { float db = b - 1.0f; acc += db * db + dd * dd; } // target bar = (1,0)
        else        { float e = b - dd;    acc += 0.5f * e * e; }
    }
    if (tid == 0 && K2 > mn) acc += 0.5f * (float)(K2 - mn);           // unmatched (1,0) bars
    for (int off = 32; off > 0; off >>= 1) acc += __shfl_down(acc, off);
    __shared__ float red[4];
    const int wid = tid >> 6, lane = tid & 63;
    if (lane == 0) red[wid] = acc;
    __syncthreads();
    if (tid == 0) atomicAdd(out, 0.25f * (red[0] + red[1] + red[2] + red[3]));
}

extern "C" void kernel_launch(void* const* d_in, const int* in_sizes, int n_in,
                              void* d_out, int out_size, void* d_ws, size_t ws_size,
                              hipStream_t stream) {
    const float* logits = (const float*)d_in[0];   // (4,2,64,64) f32
    const float* target = (const float*)d_in[1];   // (4,64,64) f32
    float* wsB = (float*)d_ws;                     // 4 pred diagrams * 2 * 2048 floats
    int* wsK = (int*)((char*)d_ws + (size_t)4 * 2 * NBARS * sizeof(float));

    hipMemsetAsync(d_out, 0, sizeof(float), stream);
    hipLaunchKernelGGL(ph0_kernel, dim3(8), dim3(NT), 0, stream,
                       logits, target, wsB, wsK);
    hipLaunchKernelGGL(betti_loss_kernel, dim3(4), dim3(256), 0, stream,
                       wsB, wsK, (float*)d_out);
}

// Round 7
// 133.912 us; speedup vs baseline: 24.9670x; 1.3202x over previous
//
#include <hip/hip_runtime.h>

#define N_PIX 4096
#define HW 64
#define NT 1024
#define TINF 0xFFFFFFFFu
#define K2TAG 0x51170000u

// s_mem layout (u32 word offsets). Aliasing is phase-disjoint (barriers between).
#define OFF_KA   0       // u32[4096] radix keys A (pred)
#define OFF_KB   4096    // u32[4096] radix keys B; later u64 BK[2048] (bar keys)
#define OFF_PA   8192    // u16[4096] payload A (pixel ids)
#define OFF_PB   10240   // u16[4096] payload B; later u32 BAR[2048]
#define OFF_CNT  12288   // u16[16384] radix counts (u32[8192]); later T u32[4096] (low half)
#define OFF_VRK  16384   // f32[4096] value-by-rank (upper half of CNT region)
#define OFF_RNK  20480   // u16[4096] pixel -> rank
#define OFF_HIST 22528   // u32[256] select histogram
#define OFF_SCR  22784   // u32[32] scan/reduce scratch
#define SMEM_U32 22816

__device__ __forceinline__ unsigned fmap_desc(float f) {
    unsigned u = __float_as_uint(f);
    unsigned m = u ^ (((unsigned)((int)u >> 31)) | 0x80000000u); // ascending map
    return ~m;                                                   // descending
}
__device__ __forceinline__ float funmap_desc(unsigned k) {
    unsigned m = ~k;
    unsigned u = (m & 0x80000000u) ? (m ^ 0x80000000u) : ~m;
    return __uint_as_float(u);
}

// Lock-free triplet merge over ranks (0 = eldest). T[x] = (s<<12)|v: comp of x
// merges at saddle-rank s into chain of v (v < x). TINF = alive. Links point
// younger->elder (acyclic); a node's s only decreases (CAS-guarded).
__device__ __forceinline__ int tm_rep(unsigned* T, int u, int w) {
    while (true) {
        unsigned t = *(volatile unsigned*)&T[u];
        if (t == TINF) break;
        int s = (int)(t >> 12);
        if (s > w) break;
        u = (int)(t & 0xFFFu);
    }
    return u;
}
__device__ void tm_merge(unsigned* T, int a, int b, int w) {
    for (int guard = 0; guard < (1 << 20); ++guard) {
        int ra = tm_rep(T, a, w);
        int rb = tm_rep(T, b, w);
        if (ra == rb) return;
        if (ra < rb) { int t = ra; ra = rb; rb = t; }   // ra = younger
        unsigned old = *(volatile unsigned*)&T[ra];
        if (old != TINF && (int)(old >> 12) <= w) continue;  // stale rep
        unsigned nv = ((unsigned)w << 12) | (unsigned)rb;
        if (atomicCAS(&T[ra], old, nv) != old) continue;
        if (old == TINF) return;
        a = rb; b = (int)(old & 0xFFFu); w = (int)(old >> 12); // re-hang displaced
    }
}

extern "C" __global__ void __launch_bounds__(NT)
betti_fused_kernel(const float* __restrict__ logits,
                   const float* __restrict__ target,
                   float* __restrict__ out, unsigned* __restrict__ wsK) {
    __shared__ unsigned s_mem[SMEM_U32];
    __shared__ int s_cnt, s_done, s_rem, s_m, s_bin, s_bcnt, s_K2;
    __shared__ unsigned long long s_pref, s_theta;

    unsigned*            KA   = s_mem + OFF_KA;
    unsigned*            KB   = s_mem + OFF_KB;
    unsigned short*      PA   = (unsigned short*)(s_mem + OFF_PA);
    unsigned short*      PB   = (unsigned short*)(s_mem + OFF_PB);
    unsigned short*      CNT  = (unsigned short*)(s_mem + OFF_CNT);
    unsigned*            T    = s_mem + OFF_CNT;
    float*               VRK  = (float*)(s_mem + OFF_VRK);
    unsigned short*      RNK  = (unsigned short*)(s_mem + OFF_RNK);
    unsigned*            HIST = s_mem + OFF_HIST;
    unsigned*            SCR  = s_mem + OFF_SCR;
    unsigned long long*  BK   = (unsigned long long*)(s_mem + OFF_KB);
    unsigned*            BAR  = s_mem + OFF_PB;

    const int d = blockIdx.x;        // 0..3 pred sample, 4..7 target sample
    const int smp = d & 3;
    const bool pred = d < 4;
    const int tid = threadIdx.x;
    const int lane = tid & 63, wid = tid >> 6;

    if (pred) {
        // ---- P0: softmax fg -> 32-bit desc keys, payload = pixel id ----
        for (int p = tid; p < N_PIX; p += NT) {
            float l0 = logits[smp * 2 * N_PIX + p];
            float l1 = logits[smp * 2 * N_PIX + N_PIX + p];
            float mx = fmaxf(l0, l1);
            float e0 = expf(l0 - mx), e1 = expf(l1 - mx);
            float v = e1 / (e0 + e1);
            KA[p] = fmap_desc(v);
            PA[p] = (unsigned short)p;
        }
        __syncthreads();
        // ---- P1: stable LSD radix sort, 4 passes x 8 bits ----
        unsigned* src = KA; unsigned* dst = KB;
        unsigned short* ps = PA; unsigned short* pd = PB;
        for (int pass = 0; pass < 4; ++pass) {
            const int shift = pass * 8;
            // CNT is u32[8192] (16384 u16) -- zero ALL of it (r6 bug: only 4096)
            for (int q = tid; q < 8192; q += NT) ((unsigned*)CNT)[q] = 0;
            __syncthreads();
            int dg[4], rk[4];
            #pragma unroll
            for (int i = 0; i < 4; ++i) {
                unsigned k = src[i * NT + tid];
                int dgi = (int)((k >> shift) & 255u);
                unsigned long long mm = ~0ull;
                #pragma unroll
                for (int b = 0; b < 8; ++b) {
                    unsigned long long bm = __ballot((dgi >> b) & 1);
                    mm &= ((dgi >> b) & 1) ? bm : ~bm;
                }
                rk[i] = __popcll(mm & ((1ull << lane) - 1ull));
                if (rk[i] == 0)
                    CNT[dgi * 64 + i * 16 + wid] = (unsigned short)__popcll(mm);
                dg[i] = dgi;
            }
            __syncthreads();
            // flat exclusive scan of 16384 u16 (digit-major => positions direct)
            unsigned vv[8]; int lsum = 0;
            #pragma unroll
            for (int q = 0; q < 8; ++q) {
                vv[q] = ((unsigned*)CNT)[tid * 8 + q];
                lsum += (int)(vv[q] & 0xFFFFu) + (int)(vv[q] >> 16);
            }
            int x = lsum;
            #pragma unroll
            for (int off = 1; off < 64; off <<= 1) { int t2 = __shfl_up(x, off); if (lane >= off) x += t2; }
            if (lane == 63) SCR[wid] = (unsigned)x;
            __syncthreads();
            if (tid < 16) {
                int y = (int)SCR[tid]; int z = y;
                #pragma unroll
                for (int off = 1; off < 16; off <<= 1) { int t2 = __shfl_up(z, off); if (tid >= off) z += t2; }
                SCR[tid] = (unsigned)(z - y);
            }
            __syncthreads();
            int run = (int)SCR[wid] + (x - lsum);
            #pragma unroll
            for (int q = 0; q < 8; ++q) {
                int lo = (int)(vv[q] & 0xFFFFu), hi = (int)(vv[q] >> 16);
                ((unsigned*)CNT)[tid * 8 + q] = (unsigned)run | ((unsigned)(run + lo) << 16);
                run += lo + hi;
            }
            __syncthreads();
            #pragma unroll
            for (int i = 0; i < 4; ++i) {
                unsigned k = src[i * NT + tid];
                unsigned short p = ps[i * NT + tid];
                int pos = (int)CNT[dg[i] * 64 + i * 16 + wid] + rk[i];
                dst[pos] = k; pd[pos] = p;
            }
            __syncthreads();
            unsigned* tk = src; src = dst; dst = tk;
            unsigned short* tp = ps; ps = pd; pd = tp;
        }
        // result in KA/PA. Build rank map, values-by-rank, init triplet slots.
        for (int t = tid; t < N_PIX; t += NT) {
            VRK[t] = funmap_desc(KA[t]);
            RNK[PA[t]] = (unsigned short)t;
            T[t] = TINF;
        }
        if (tid == 0) s_cnt = 0;
        __syncthreads();
    } else {
        // ---- TARGET: binary ranks via bit-count scan (1s first by idx, then 0s) ----
        const float* tg = target + smp * N_PIX;
        int o[4]; int ls = 0;
        #pragma unroll
        for (int j = 0; j < 4; ++j) { int p = 4 * tid + j; o[j] = (tg[p] > 0.5f) ? 1 : 0; ls += o[j]; }
        int x = ls;
        #pragma unroll
        for (int off = 1; off < 64; off <<= 1) { int t2 = __shfl_up(x, off); if (lane >= off) x += t2; }
        if (lane == 63) SCR[wid] = (unsigned)x;
        __syncthreads();
        if (tid < 16) {
            int y = (int)SCR[tid]; int z = y;
            #pragma unroll
            for (int off = 1; off < 16; off <<= 1) { int t2 = __shfl_up(z, off); if (tid >= off) z += t2; }
            SCR[tid] = (unsigned)(z - y);
            if (tid == 15) SCR[16] = (unsigned)z;
        }
        __syncthreads();
        int run = (int)SCR[wid] + (x - ls);
        const int n1 = (int)SCR[16];
        #pragma unroll
        for (int j = 0; j < 4; ++j) {
            int p = 4 * tid + j;
            int rkv = o[j] ? run : (n1 + p - run);
            RNK[p] = (unsigned short)rkv;
            run += o[j];
        }
        for (int t = tid; t < N_PIX; t += NT) {
            VRK[t] = (t < n1) ? 1.0f : 0.0f;
            T[t] = TINF;
        }
        if (tid == 0) s_cnt = 0;
        __syncthreads();
    }

    // ---- P2: lock-free triplet merge over all 8064 adjacencies (shared) ----
    for (int p = tid; p < N_PIX; p += NT) {
        int r = p >> 6, c = p & 63;
        int rp = RNK[p];
        if (c < 63) { int rq = RNK[p + 1];  tm_merge(T, rp, rq, max(rp, rq)); }
        if (r < 63) { int rq = RNK[p + HW]; tm_merge(T, rp, rq, max(rp, rq)); }
    }
    __syncthreads();

    if (!pred) {
        // ---- TARGET: K2 = count of positive bars (+ essential), publish ----
        int cnt = 0;
        for (int t = tid; t < N_PIX; t += NT)
            if (t > 0) { unsigned tv = T[t]; int sd = (int)(tv >> 12); cnt += (VRK[t] > VRK[sd]) ? 1 : 0; }
        for (int off = 32; off > 0; off >>= 1) cnt += __shfl_down(cnt, off);
        if (lane == 0) SCR[wid] = (unsigned)cnt;
        __syncthreads();
        if (tid == 0) {
            int K2 = 0;
            for (int w2 = 0; w2 < 16; ++w2) K2 += (int)SCR[w2];
            if (VRK[0] > VRK[N_PIX - 1]) K2 += 1;    // essential
            __threadfence();
            atomicExch(&wsK[smp], K2TAG | (unsigned)K2);
        }
        return;
    }

    // ---- PRED P3: collect positive bars + 64-bit selection keys ----
    for (int t = tid; t < N_PIX; t += NT) {
        bool isb = false; unsigned rec = 0; unsigned long long bkv = 0;
        if (t > 0) {
            unsigned tv = T[t]; int sd = (int)(tv >> 12);
            float bv = VRK[t], dv = VRK[sd];
            if (bv > dv) {
                isb = true;
                rec = ((unsigned)t << 16) | (unsigned)sd;
                float pers = bv - dv;
                bkv = ((unsigned long long)(~__float_as_uint(pers)) << 32) |
                      ((unsigned long long)t << 12) | (unsigned long long)sd;
            }
        }
        unsigned long long mk = __ballot(isb);
        int nb = __popcll(mk);
        int base = 0;
        if (lane == 0 && nb) base = atomicAdd(&s_cnt, nb);
        base = __shfl(base, 0);
        if (isb) {
            int pos = base + __popcll(mk & ((1ull << lane) - 1ull));
            BAR[pos] = rec; BK[pos] = bkv;
        }
    }
    __syncthreads();
    if (tid == 0 && VRK[0] > VRK[N_PIX - 1]) {
        int e = s_cnt++;
        float pers = VRK[0] - VRK[N_PIX - 1];
        BAR[e] = (0u << 16) | (unsigned)(N_PIX - 1);
        BK[e] = ((unsigned long long)(~__float_as_uint(pers)) << 32) |
                (unsigned long long)(N_PIX - 1);
    }
    __syncthreads();
    const int K1 = s_cnt;

    // ---- spin for target count (target blocks co-resident & much faster) ----
    if (tid == 0) {
        unsigned v;
        do { v = atomicAdd(&wsK[smp], 0u);
             __builtin_amdgcn_s_sleep(8);
        } while ((v >> 16) != (K2TAG >> 16));
        int K2 = (int)(v & 0xFFFFu);
        s_K2 = K2;
        s_m = min(K1, K2);
    }
    __syncthreads();
    const int m = s_m;

    // ---- P4: radix-select m-th smallest 64-bit key -> theta ----
    unsigned long long theta = 0ull;
    if (m > 0) {
        if (tid == 0) { s_pref = 0ull; s_rem = m - 1; s_done = 0; }
        __syncthreads();
        for (int by = 7; by >= 0; --by) {
            if (s_done) break;                       // uniform post-barrier read
            if (tid < 256) HIST[tid] = 0;
            __syncthreads();
            unsigned long long pref = s_pref; int rem = s_rem;
            unsigned long long mhi = (by == 7) ? 0ull : (~0ull << ((by + 1) * 8));
            for (int e = tid; e < K1; e += NT) {
                unsigned long long k = BK[e];
                if ((k & mhi) == pref)
                    atomicAdd(&HIST[(unsigned)((k >> (by * 8)) & 255ull)], 1u);
            }
            __syncthreads();
            if (tid < 64) {
                unsigned h0 = HIST[4 * tid], h1 = HIST[4 * tid + 1];
                unsigned h2 = HIST[4 * tid + 2], h3 = HIST[4 * tid + 3];
                int lsx = (int)(h0 + h1 + h2 + h3);
                int xx = lsx;
                #pragma unroll
                for (int off = 1; off < 64; off <<= 1) { int t2 = __shfl_up(xx, off); if (tid >= off) xx += t2; }
                int excl = xx - lsx;
                if (rem >= excl && rem < excl + lsx) {
                    int rr = rem - excl; int b;
                    if (rr < (int)h0) b = 4 * tid;
                    else if (rr < (int)(h0 + h1)) { b = 4 * tid + 1; rr -= (int)h0; }
                    else if (rr < (int)(h0 + h1 + h2)) { b = 4 * tid + 2; rr -= (int)(h0 + h1); }
                    else { b = 4 * tid + 3; rr -= (int)(h0 + h1 + h2); }
                    s_bin = b; s_rem = rr; s_bcnt = (int)HIST[b];
                }
            }
            __syncthreads();
            unsigned long long npref = pref | ((unsigned long long)(unsigned)s_bin << (by * 8));
            if (tid == 0) s_pref = npref;
            if (s_bcnt == 1) {
                unsigned long long mcur = mhi | (0xFFull << (by * 8));
                for (int e = tid; e < K1; e += NT) {
                    unsigned long long k = BK[e];
                    if ((k & mcur) == npref) s_theta = k;   // unique writer
                }
                if (tid == 0) s_done = 1;
            }
            __syncthreads();
        }
        theta = s_theta;   // keys unique => early-exit guaranteed by byte 0
    }

    // ---- P5: loss (matched vs target bar (1,0); unmatched -> diagonal) ----
    float acc = 0.0f;
    for (int e = tid; e < K1; e += NT) {
        unsigned rec = BAR[e];
        float b = VRK[rec >> 16], dd = VRK[rec & 0xFFFFu];
        bool mt = (m > 0) && (BK[e] <= theta);
        float v1 = (b - 1.0f) * (b - 1.0f) + dd * dd;
        float v0 = 0.5f * (b - dd) * (b - dd);
        acc += mt ? v1 : v0;
    }
    if (tid == 0 && s_K2 > m) acc += 0.5f * (float)(s_K2 - m);
    for (int off = 32; off > 0; off >>= 1) acc += __shfl_down(acc, off);
    if (lane == 0) ((float*)SCR)[wid] = acc;
    __syncthreads();
    if (tid == 0) {
        float s = 0.0f;
        for (int w2 = 0; w2 < 16; ++w2) s += ((float*)SCR)[w2];
        atomicAdd(out, 0.25f * s);
    }
}

extern "C" void kernel_launch(void* const* d_in, const int* in_sizes, int n_in,
                              void* d_out, int out_size, void* d_ws, size_t ws_size,
                              hipStream_t stream) {
    const float* logits = (const float*)d_in[0];   // (4,2,64,64) f32
    const float* target = (const float*)d_in[1];   // (4,64,64) f32
    unsigned* wsK = (unsigned*)d_ws;               // 4 tagged K2 slots

    hipMemsetAsync(d_out, 0, sizeof(float), stream);
    hipLaunchKernelGGL(betti_fused_kernel, dim3(8), dim3(NT), 0, stream,
                       logits, target, (float*)d_out, wsK);
}